// Round 6
// baseline (282.500 us; speedup 1.0000x reference)
//
#include <hip/hip_runtime.h>

#define NS  262144
#define NN  24
#define CI  32
#define HW  32
#define SPB 32                    // samples per block
#define NROWS (SPB * NN)          // 768 (s,n) rows per block tile
#define NCHUNK (NROWS * 8)        // 6144 16B-chunks = 96KB per block tile

typedef __fp16 fp16x2v __attribute__((ext_vector_type(2)));
typedef _Float16 half2v __attribute__((ext_vector_type(2)));
typedef _Float16 half8 __attribute__((ext_vector_type(8)));
typedef float f32x4 __attribute__((ext_vector_type(4)));
typedef unsigned int u32x4 __attribute__((ext_vector_type(4)));
typedef unsigned int u32x2 __attribute__((ext_vector_type(2)));

// f16 fragments of W1^T used as the MFMA *A* operand:
// g_w1f[n][half][lane][i] = W1[n][c=(lane>>4)*8+i][w=half*16+(lane&15)]
__device__ alignas(16) unsigned short g_w1f[NN * 2 * 64 * 8];

__global__ void pack_w1(const float* __restrict__ W1) {
  int idx = blockIdx.x * 256 + threadIdx.x;
  if (idx >= NN * 2 * 64 * 8) return;
  int i    = idx & 7;
  int lane = (idx >> 3) & 63;
  int hf   = (idx >> 9) & 1;
  int n    = idx >> 10;
  int k = (lane >> 4) * 8 + i;
  int w = hf * 16 + (lane & 15);
  _Float16 v = (_Float16)W1[(n * CI + k) * HW + w];
  g_w1f[idx] = __builtin_bit_cast(unsigned short, v);
}

__device__ __forceinline__ unsigned pkrtz(float a, float b) {
#if __has_builtin(__builtin_amdgcn_cvt_pkrtz)
  fp16x2v p = __builtin_amdgcn_cvt_pkrtz(a, b);
  return __builtin_bit_cast(unsigned, p);
#else
  half2v p;
  p[0] = (_Float16)a;
  p[1] = (_Float16)b;
  return __builtin_bit_cast(unsigned, p);
#endif
}

__global__ __launch_bounds__(256) void mlp_mfma(
    const float* __restrict__ h, const int* __restrict__ valid,
    const float* __restrict__ b1, const float* __restrict__ W2,
    const float* __restrict__ b2, float* __restrict__ out) {
  // f16 relu(h) tile, layout [n][s][c] (+XOR swizzle), 48 KB
  __shared__ alignas(16) unsigned short lds[NN * SPB * CI];

  const int tid = threadIdx.x;
  const int sB  = blockIdx.x * SPB;
  const float* __restrict__ gb = h + (size_t)sB * (NN * CI);
  const int*   __restrict__ vb = valid + sB * NN;

  // ---- Stage: 96KB CONTIGUOUS HBM read -> relu -> f16 -> LDS transpose.
  // Invalid rows: skip the fetch, write zeros (output masked later anyway).
#pragma unroll 8
  for (int rd = 0; rd < NCHUNK / 256; ++rd) {   // 24 rounds
    const int chunk = rd * 256 + tid;           // 16B chunk within tile
    const int rloc  = chunk >> 3;               // row = s_local*NN + n
    const int c0    = (chunk & 7) * 4;          // first float of chunk in row
    const int v     = vb[rloc];
    f32x4 d = {0.f, 0.f, 0.f, 0.f};
    if (v) d = *(const f32x4*)(gb + (size_t)chunk * 4);
    const int sl = rloc / NN;
    const int n  = rloc - sl * NN;
    unsigned p0 = pkrtz(fmaxf(d[0], 0.f), fmaxf(d[1], 0.f));
    unsigned p1 = pkrtz(fmaxf(d[2], 0.f), fmaxf(d[3], 0.f));
    int byte = n * (SPB * CI * 2) + sl * (CI * 2) + c0 * 2;
    byte ^= (n & 7) << 6;                       // write-conflict swizzle
    *(u32x2*)((char*)lds + byte) = (u32x2){p0, p1};
  }
  __syncthreads();

  // ---- Compute: wave wv owns nodes [wv*6, wv*6+6), 2 sample-halves each
  const int lane = tid & 63;
  const int wv   = tid >> 6;
  const int r    = lane & 15;    // B col = sample; A row = hidden w
  const int q    = lane >> 4;    // k-chunk group; C row-group

  for (int ni = 0; ni < 6; ++ni) {
    const int n = wv * 6 + ni;
    half8 Af0 = __builtin_bit_cast(half8,
        *(const u32x4*)&g_w1f[((n * 2 + 0) * 64 + lane) * 8]);
    half8 Af1 = __builtin_bit_cast(half8,
        *(const u32x4*)&g_w1f[((n * 2 + 1) * 64 + lane) * 8]);
    f32x4 b1a = *(const f32x4*)&b1[n * HW + q * 4];
    f32x4 b1b = *(const f32x4*)&b1[n * HW + 16 + q * 4];
    f32x4 w2a = *(const f32x4*)&W2[n * HW + q * 4];
    f32x4 w2b = *(const f32x4*)&W2[n * HW + 16 + q * 4];
    float b2n = b2[n];

#pragma unroll
    for (int sh = 0; sh < 2; ++sh) {
      int byte = n * (SPB * CI * 2) + (sh * 16 + r) * (CI * 2) + q * 16;
      byte ^= (n & 7) << 6;
      half8 Hf = *(const half8*)((const char*)lds + byte);  // ds_read_b128

      f32x4 c0 = {b1a[0], b1a[1], b1a[2], b1a[3]};
      f32x4 c1 = {b1b[0], b1b[1], b1b[2], b1b[3]};
      c0 = __builtin_amdgcn_mfma_f32_16x16x32_f16(Af0, Hf, c0, 0, 0, 0);
      c1 = __builtin_amdgcn_mfma_f32_16x16x32_f16(Af1, Hf, c1, 0, 0, 0);

      float p = 0.f;
#pragma unroll
      for (int i = 0; i < 4; ++i) {
        p = fmaf(fmaxf(c0[i], 0.f), w2a[i], p);
        p = fmaf(fmaxf(c1[i], 0.f), w2b[i], p);
      }
      p += __shfl_xor(p, 16);
      p += __shfl_xor(p, 32);

      if (lane < 16) {
        const int srow = sB + sh * 16 + r;
        const int vv = valid[srow * NN + n];   // L1-hot (staged this block)
        out[(size_t)srow * NN + n] = vv ? (p + b2n) : 0.0f;
      }
    }
  }
}

extern "C" void kernel_launch(void* const* d_in, const int* in_sizes, int n_in,
                              void* d_out, int out_size, void* d_ws, size_t ws_size,
                              hipStream_t stream) {
  const float* h     = (const float*)d_in[0];
  const int*   valid = (const int*)d_in[1];
  const float* W1    = (const float*)d_in[2];
  const float* b1    = (const float*)d_in[3];
  const float* W2    = (const float*)d_in[4];
  const float* b2    = (const float*)d_in[5];
  float* out = (float*)d_out;

  hipLaunchKernelGGL(pack_w1, dim3((NN * 2 * 64 * 8 + 255) / 256), dim3(256),
                     0, stream, W1);
  hipLaunchKernelGGL(mlp_mfma, dim3(NS / SPB), dim3(256), 0, stream,
                     h, valid, b1, W2, b2, out);
}

// Round 7
// 210.540 us; speedup vs baseline: 1.3418x; 1.3418x over previous
//
#include <hip/hip_runtime.h>

#define NS  262144
#define NN  24
#define CI  32
#define HW  32
#define SPB 32                    // samples per block; tile = 96KB f32 / 48KB f16

typedef __fp16 fp16x2v __attribute__((ext_vector_type(2)));
typedef _Float16 half2v __attribute__((ext_vector_type(2)));
typedef _Float16 half8 __attribute__((ext_vector_type(8)));
typedef float f32x4 __attribute__((ext_vector_type(4)));
typedef unsigned int u32x4 __attribute__((ext_vector_type(4)));

// f16 fragments of W1^T used as the MFMA *A* operand:
// g_w1f[n][half][lane][i] = W1[n][c=(lane>>4)*8+i][w=half*16+(lane&15)]
__device__ alignas(16) unsigned short g_w1f[NN * 2 * 64 * 8];

__global__ void pack_w1(const float* __restrict__ W1) {
  int idx = blockIdx.x * 256 + threadIdx.x;
  if (idx >= NN * 2 * 64 * 8) return;
  int i    = idx & 7;
  int lane = (idx >> 3) & 63;
  int hf   = (idx >> 9) & 1;
  int n    = idx >> 10;
  int k = (lane >> 4) * 8 + i;
  int w = hf * 16 + (lane & 15);
  _Float16 v = (_Float16)W1[(n * CI + k) * HW + w];
  g_w1f[idx] = __builtin_bit_cast(unsigned short, v);
}

__device__ __forceinline__ unsigned pkrtz(float a, float b) {
#if __has_builtin(__builtin_amdgcn_cvt_pkrtz)
  fp16x2v p = __builtin_amdgcn_cvt_pkrtz(a, b);
  return __builtin_bit_cast(unsigned, p);
#else
  half2v p;
  p[0] = (_Float16)a;
  p[1] = (_Float16)b;
  return __builtin_bit_cast(unsigned, p);
#endif
}

__global__ __launch_bounds__(256) void mlp_mfma(
    const float* __restrict__ h, const int* __restrict__ valid,
    const float* __restrict__ b1, const float* __restrict__ W2,
    const float* __restrict__ b2, float* __restrict__ out) {
  // f16 relu(h) tile, layout [n][s][c] (+XOR swizzle), 48 KB
  __shared__ alignas(16) unsigned short lds[NN * SPB * CI];

  const int tid = threadIdx.x;
  const int sB  = blockIdx.x * SPB;
  const float* __restrict__ gb = h + (size_t)sB * (NN * CI);

  // ---- Stage: read the FULL 96KB tile as a pure contiguous stream —
  // NO valid-predication (that was the ~2 TB/s killer: 50%-density 128B
  // holes thrash DRAM pages). Invalid samples' data is harmless garbage:
  // their C columns are masked at the store.
#pragma unroll 4
  for (int rd = 0; rd < 12; ++rd) {
    const int c32 = rd * 256 + tid;       // 32B-chunk index within tile
    const int row = c32 >> 2;             // row = sl*NN + n
    const int q   = c32 & 3;              // 8-float quarter within row
    const int sl  = row / NN;             // compiler magic-mul
    const int n   = row - sl * NN;
    const float* hp = gb + (size_t)c32 * 8;
    f32x4 d0 = *(const f32x4*)hp;
    f32x4 d1 = *(const f32x4*)(hp + 4);
    u32x4 u;
    u[0] = pkrtz(fmaxf(d0[0], 0.f), fmaxf(d0[1], 0.f));
    u[1] = pkrtz(fmaxf(d0[2], 0.f), fmaxf(d0[3], 0.f));
    u[2] = pkrtz(fmaxf(d1[0], 0.f), fmaxf(d1[1], 0.f));
    u[3] = pkrtz(fmaxf(d1[2], 0.f), fmaxf(d1[3], 0.f));
    int byte = n * (SPB * CI * 2) + sl * (CI * 2) + q * 16;
    byte ^= (n & 7) << 6;                 // bank swizzle (write & read agree)
    *(u32x4*)((char*)lds + byte) = u;
  }
  __syncthreads();

  // ---- Compute: wave wv owns nodes [wv*6, wv*6+6), 2 sample-halves each
  const int lane = tid & 63;
  const int wv   = tid >> 6;
  const int r    = lane & 15;    // B col = sample; A row = hidden w
  const int q    = lane >> 4;    // k-chunk group; C row-group

  for (int ni = 0; ni < 6; ++ni) {
    const int n = wv * 6 + ni;
    half8 Af0 = __builtin_bit_cast(half8,
        *(const u32x4*)&g_w1f[((n * 2 + 0) * 64 + lane) * 8]);
    half8 Af1 = __builtin_bit_cast(half8,
        *(const u32x4*)&g_w1f[((n * 2 + 1) * 64 + lane) * 8]);
    f32x4 b1a = *(const f32x4*)&b1[n * HW + q * 4];
    f32x4 b1b = *(const f32x4*)&b1[n * HW + 16 + q * 4];
    f32x4 w2a = *(const f32x4*)&W2[n * HW + q * 4];
    f32x4 w2b = *(const f32x4*)&W2[n * HW + 16 + q * 4];
    float b2n = b2[n];

#pragma unroll
    for (int sh = 0; sh < 2; ++sh) {
      int byte = n * (SPB * CI * 2) + (sh * 16 + r) * (CI * 2) + q * 16;
      byte ^= (n & 7) << 6;
      half8 Hf = *(const half8*)((const char*)lds + byte);  // ds_read_b128

      f32x4 c0 = {b1a[0], b1a[1], b1a[2], b1a[3]};
      f32x4 c1 = {b1b[0], b1b[1], b1b[2], b1b[3]};
      c0 = __builtin_amdgcn_mfma_f32_16x16x32_f16(Af0, Hf, c0, 0, 0, 0);
      c1 = __builtin_amdgcn_mfma_f32_16x16x32_f16(Af1, Hf, c1, 0, 0, 0);

      float p = 0.f;
#pragma unroll
      for (int i = 0; i < 4; ++i) {
        p = fmaf(fmaxf(c0[i], 0.f), w2a[i], p);
        p = fmaf(fmaxf(c1[i], 0.f), w2b[i], p);
      }
      p += __shfl_xor(p, 16);
      p += __shfl_xor(p, 32);

      if (lane < 16) {
        const int srow = sB + sh * 16 + r;
        const int vv = valid[srow * NN + n];
        out[(size_t)srow * NN + n] = vv ? (p + b2n) : 0.0f;
      }
    }
  }
}

extern "C" void kernel_launch(void* const* d_in, const int* in_sizes, int n_in,
                              void* d_out, int out_size, void* d_ws, size_t ws_size,
                              hipStream_t stream) {
  const float* h     = (const float*)d_in[0];
  const int*   valid = (const int*)d_in[1];
  const float* W1    = (const float*)d_in[2];
  const float* b1    = (const float*)d_in[3];
  const float* W2    = (const float*)d_in[4];
  const float* b2    = (const float*)d_in[5];
  float* out = (float*)d_out;

  hipLaunchKernelGGL(pack_w1, dim3((NN * 2 * 64 * 8 + 255) / 256), dim3(256),
                     0, stream, W1);
  hipLaunchKernelGGL(mlp_mfma, dim3(NS / SPB), dim3(256), 0, stream,
                     h, valid, b1, W2, b2, out);
}